// Round 10
// baseline (150.702 us; speedup 1.0000x reference)
//
#include <hip/hip_runtime.h>

#define D 32
#define CHUNK 4096        // edges per build block
#define BWID 512          // nodes per bucket
#define BSH 9             // log2(BWID)
#define SCAN_T 256
#define SCAN_V 4
#define SCAN_CHUNK 1024

// ---------------- bf16 helpers ----------------
__device__ __forceinline__ unsigned f2bf2(float lo, float hi) {
    union { float f; unsigned u; } a, b;
    a.f = lo; b.f = hi;
    unsigned ra = a.u + 0x7FFFu + ((a.u >> 16) & 1u);   // RNE
    unsigned rb = b.u + 0x7FFFu + ((b.u >> 16) & 1u);
    return (ra >> 16) | (rb & 0xFFFF0000u);
}
__device__ __forceinline__ void bf2_unpack(unsigned u, float& lo, float& hi) {
    union { unsigned u; float f; } a, b;
    a.u = u << 16; b.u = u & 0xFFFF0000u;
    lo = a.f; hi = b.f;
}

// ================= bucketed CSR build (no global atomics) =================

__global__ void p1_count_kernel(const int* __restrict__ dst, int* __restrict__ cnt,
                                int E, int NB) {
    __shared__ int h[256];
    int blk = blockIdx.x, t = threadIdx.x;
    for (int i = t; i < 256; i += 256) h[i] = 0;
    __syncthreads();
    int base = blk * CHUNK;
    int end = min(base + CHUNK, E);
    int tbase = base + t * 16;
    #pragma unroll
    for (int k = 0; k < 4; ++k) {
        int a = tbase + k * 4;
        if (a + 3 < end) {
            int4 d = *(const int4*)(dst + a);
            atomicAdd(&h[d.x >> BSH], 1);
            atomicAdd(&h[d.y >> BSH], 1);
            atomicAdd(&h[d.z >> BSH], 1);
            atomicAdd(&h[d.w >> BSH], 1);
        } else {
            for (int e = a; e < end && e < a + 4; ++e) atomicAdd(&h[dst[e] >> BSH], 1);
        }
    }
    __syncthreads();
    for (int i = t; i < NB; i += 256) cnt[blk * NB + i] = h[i];
}

__global__ void red_kernel(const int* __restrict__ cnt, int* __restrict__ btot,
                           int GB, int NB) {
    __shared__ int s[256];
    int b = blockIdx.x, t = threadIdx.x;
    int acc = 0;
    for (int g = t; g < GB; g += 256) acc += cnt[g * NB + b];
    s[t] = acc;
    __syncthreads();
    for (int off = 128; off > 0; off >>= 1) {
        if (t < off) s[t] += s[t + off];
        __syncthreads();
    }
    if (t == 0) btot[b] = s[0];
}

__global__ void scanb_kernel(const int* __restrict__ btot, int* __restrict__ bbase, int NB) {
    __shared__ int s[256];
    int t = threadIdx.x;
    int v = (t < NB) ? btot[t] : 0;
    s[t] = v;
    __syncthreads();
    for (int off = 1; off < 256; off <<= 1) {
        int x = (t >= off) ? s[t - off] : 0;
        __syncthreads();
        s[t] += x;
        __syncthreads();
    }
    if (t < NB) bbase[t] = s[t] - v;
    if (t == NB - 1) bbase[NB] = s[t];
}

__global__ void off_kernel(const int* __restrict__ cnt, const int* __restrict__ bbase,
                           int* __restrict__ off, int GB, int NB) {
    __shared__ int st[256];
    int b = blockIdx.x, t = threadIdx.x;
    int g0 = 2 * t, g1 = 2 * t + 1;
    int c0 = (g0 < GB) ? cnt[g0 * NB + b] : 0;
    int c1 = (g1 < GB) ? cnt[g1 * NB + b] : 0;
    int pair = c0 + c1;
    st[t] = pair;
    __syncthreads();
    for (int o = 1; o < 256; o <<= 1) {
        int x = (t >= o) ? st[t - o] : 0;
        __syncthreads();
        st[t] += x;
        __syncthreads();
    }
    int ex = bbase[b] + st[t] - pair;
    if (g0 < GB) off[g0 * NB + b] = ex;
    if (g1 < GB) off[g1 * NB + b] = ex + c0;
}

__global__ void p3_scatter_kernel(const int* __restrict__ src, const int* __restrict__ dst,
                                  const int* __restrict__ off, unsigned* __restrict__ ebuf,
                                  int E, int NB) {
    __shared__ int cur[256];
    int blk = blockIdx.x, t = threadIdx.x;
    for (int i = t; i < NB; i += 256) cur[i] = off[blk * NB + i];
    __syncthreads();
    int base = blk * CHUNK;
    int end = min(base + CHUNK, E);
    int tbase = base + t * 16;
    #pragma unroll
    for (int k = 0; k < 4; ++k) {
        int a = tbase + k * 4;
        if (a + 3 < end) {
            int4 d = *(const int4*)(dst + a);
            int4 s = *(const int4*)(src + a);
            int p0 = atomicAdd(&cur[d.x >> BSH], 1);
            int p1 = atomicAdd(&cur[d.y >> BSH], 1);
            int p2 = atomicAdd(&cur[d.z >> BSH], 1);
            int p3 = atomicAdd(&cur[d.w >> BSH], 1);
            ebuf[p0] = ((unsigned)(d.x & (BWID - 1)) << 23) | (unsigned)s.x;
            ebuf[p1] = ((unsigned)(d.y & (BWID - 1)) << 23) | (unsigned)s.y;
            ebuf[p2] = ((unsigned)(d.z & (BWID - 1)) << 23) | (unsigned)s.z;
            ebuf[p3] = ((unsigned)(d.w & (BWID - 1)) << 23) | (unsigned)s.w;
        } else {
            for (int e = a; e < end && e < a + 4; ++e) {
                int dv = dst[e];
                int p = atomicAdd(&cur[dv >> BSH], 1);
                ebuf[p] = ((unsigned)(dv & (BWID - 1)) << 23) | (unsigned)src[e];
            }
        }
    }
}

// ---- P4: per-bucket finalize -> row_start/row_end/norm/csr + bf16 half-buffers ----
__global__ void p4_kernel(const unsigned* __restrict__ ebuf, const int* __restrict__ bbase,
                          int* __restrict__ row_start, int* __restrict__ row_end,
                          float* __restrict__ norm, int* __restrict__ csr_src,
                          const float* __restrict__ feat,
                          unsigned* __restrict__ A1h0, unsigned* __restrict__ A1h1, int N) {
    __shared__ int deg2[BWID];
    __shared__ int rs[BWID];
    __shared__ int st[256];
    int b = blockIdx.x, t = threadIdx.x;
    int node0 = b << BSH;
    int nn = min(BWID, N - node0);
    int e0 = bbase[b], e1 = bbase[b + 1];
    deg2[t] = 0; deg2[t + 256] = 0;
    __syncthreads();
    for (int j = e0 + t; j < e1; j += 256)
        atomicAdd(&deg2[ebuf[j] >> 23], 1);
    __syncthreads();
    int d0 = deg2[2 * t], d1 = deg2[2 * t + 1];
    int pair = d0 + d1;
    st[t] = pair;
    __syncthreads();
    for (int off = 1; off < 256; off <<= 1) {
        int v = (t >= off) ? st[t - off] : 0;
        __syncthreads();
        st[t] += v;
        __syncthreads();
    }
    int ex = st[t] - pair;
    rs[2 * t] = ex;
    rs[2 * t + 1] = ex + d0;
    __syncthreads();
    #pragma unroll
    for (int k = 0; k < 2; ++k) {
        int i = t + k * 256;
        if (i < nn) {
            int dg = deg2[i];
            int r = e0 + rs[i];
            row_start[node0 + i] = r;
            row_end[node0 + i]   = r + dg;
            norm[node0 + i] = rsqrtf(fmaxf((float)dg, 1.0f));
        }
    }
    __syncthreads();
    for (int j = e0 + t; j < e1; j += 256) {
        unsigned v = ebuf[j];
        int dl = v >> 23;
        int p = atomicAdd(&rs[dl], 1);
        csr_src[e0 + p] = (int)(v & 0x7FFFFF);
    }
    // fused prep: bf16 halves A1h0/A1h1 = bf16(feat * norm), coalesced
    for (int c = t; c < nn * 16; c += 256) {
        int i = c >> 4, k = c & 15;          // k: u32 index over 32-feature row
        float nv = rsqrtf(fmaxf((float)deg2[i], 1.0f));
        size_t fi = (size_t)(node0 + i) * D + 2 * k;
        float2 f = *(const float2*)(feat + fi);
        unsigned u = f2bf2(f.x * nv, f.y * nv);
        if (k < 8) A1h0[(size_t)(node0 + i) * 8 + k] = u;
        else       A1h1[(size_t)(node0 + i) * 8 + (k - 8)] = u;
    }
}

// ================= fallback build (global atomics) =================
__global__ void degpos_kernel(const int* __restrict__ dst, int* __restrict__ deg,
                              int* __restrict__ pos, int E) {
    int t = blockIdx.x * blockDim.x + threadIdx.x;
    int base = t * 4;
    if (base + 3 < E) {
        int4 d = *(const int4*)(dst + base);
        int4 p;
        p.x = atomicAdd(&deg[d.x], 1);
        p.y = atomicAdd(&deg[d.y], 1);
        p.z = atomicAdd(&deg[d.z], 1);
        p.w = atomicAdd(&deg[d.w], 1);
        *(int4*)(pos + base) = p;
    } else if (base < E) {
        for (int e = base; e < E; ++e) pos[e] = atomicAdd(&deg[dst[e]], 1);
    }
}

__global__ void scan1_kernel(const int* __restrict__ deg, int* __restrict__ partial, int n) {
    __shared__ int sdata[SCAN_T];
    int base = blockIdx.x * SCAN_CHUNK + threadIdx.x * SCAN_V;
    int s = 0;
    #pragma unroll
    for (int k = 0; k < SCAN_V; ++k) { int i = base + k; if (i < n) s += deg[i]; }
    sdata[threadIdx.x] = s;
    __syncthreads();
    for (int off = SCAN_T / 2; off > 0; off >>= 1) {
        if (threadIdx.x < off) sdata[threadIdx.x] += sdata[threadIdx.x + off];
        __syncthreads();
    }
    if (threadIdx.x == 0) partial[blockIdx.x] = sdata[0];
}

__global__ void scan2_kernel(int* __restrict__ partial, int nb) {
    __shared__ int sdata[256];
    int v = (threadIdx.x < nb) ? partial[threadIdx.x] : 0;
    sdata[threadIdx.x] = v;
    __syncthreads();
    for (int off = 1; off < 256; off <<= 1) {
        int t = (threadIdx.x >= off) ? sdata[threadIdx.x - off] : 0;
        __syncthreads();
        sdata[threadIdx.x] += t;
        __syncthreads();
    }
    if (threadIdx.x < nb) partial[threadIdx.x] = sdata[threadIdx.x] - v;
}

__global__ void scan3_kernel(const int* __restrict__ deg, const int* __restrict__ partial,
                             int* __restrict__ row_start, int* __restrict__ row_end,
                             float* __restrict__ norm, int n) {
    __shared__ int sdata[SCAN_T];
    int base = blockIdx.x * SCAN_CHUNK + threadIdx.x * SCAN_V;
    int v[SCAN_V];
    int s = 0;
    #pragma unroll
    for (int k = 0; k < SCAN_V; ++k) { int i = base + k; v[k] = (i < n) ? deg[i] : 0; s += v[k]; }
    int self = s;
    sdata[threadIdx.x] = s;
    __syncthreads();
    for (int off = 1; off < SCAN_T; off <<= 1) {
        int t = (threadIdx.x >= off) ? sdata[threadIdx.x - off] : 0;
        __syncthreads();
        sdata[threadIdx.x] += t;
        __syncthreads();
    }
    int run = partial[blockIdx.x] + sdata[threadIdx.x] - self;
    #pragma unroll
    for (int k = 0; k < SCAN_V; ++k) {
        int i = base + k;
        if (i < n) {
            row_start[i] = run;
            row_end[i]   = run + v[k];
            norm[i] = rsqrtf(fmaxf((float)v[k], 1.0f));
            run += v[k];
        }
    }
}

__global__ void fillA_kernel(const int* __restrict__ src, const int* __restrict__ dst,
                             const int* __restrict__ pos, const int* __restrict__ row_start,
                             int* __restrict__ csr_src, int E) {
    int t = blockIdx.x * blockDim.x + threadIdx.x;
    int base = t * 4;
    if (base + 3 < E) {
        int4 d = *(const int4*)(dst + base);
        int4 p = *(const int4*)(pos + base);
        int4 s = *(const int4*)(src + base);
        csr_src[row_start[d.x] + p.x] = s.x;
        csr_src[row_start[d.y] + p.y] = s.y;
        csr_src[row_start[d.z] + p.z] = s.z;
        csr_src[row_start[d.w] + p.w] = s.w;
    } else if (base < E) {
        for (int e = base; e < E; ++e)
            csr_src[row_start[dst[e]] + pos[e]] = src[e];
    }
}

// prep for fallback path: bf16 halves
__global__ void prep_kernel(const float* __restrict__ feat, const float* __restrict__ norm,
                            unsigned* __restrict__ A1h0, unsigned* __restrict__ A1h1,
                            int total) {      // total = N*16 (u32 slots per row)
    int c = blockIdx.x * blockDim.x + threadIdx.x;
    if (c >= total) return;
    int v = c >> 4, k = c & 15;
    float nv = norm[v];
    size_t fi = (size_t)v * D + 2 * k;
    float2 f = *(const float2*)(feat + fi);
    unsigned u = f2bf2(f.x * nv, f.y * nv);
    if (k < 8) A1h0[(size_t)v * 8 + k] = u;
    else       A1h1[(size_t)v * 8 + (k - 8)] = u;
}

// ================= half-feature gathers: 4 rows/wave, 2 lanes/edge =================
// lane = (g = lane>>4: row 0..3, eo = (lane>>1)&7: edge slot 0..7, q = lane&1).
// Per wave-load: 32 edges in flight; per row: 8 slots x2 unroll = 16 edges in flight.
// Ah: bf16 half source, 8 u32 (16 bf16) per node = 2 uint4.

#define ACC_H(V)                                                 \
    { float lo_, hi_;                                            \
      bf2_unpack((V).x, lo_, hi_); acc[0] += lo_; acc[1] += hi_; \
      bf2_unpack((V).y, lo_, hi_); acc[2] += lo_; acc[3] += hi_; \
      bf2_unpack((V).z, lo_, hi_); acc[4] += lo_; acc[5] += hi_; \
      bf2_unpack((V).w, lo_, hi_); acc[6] += lo_; acc[7] += hi_; }

__global__ __launch_bounds__(256) void gather1_kernel(
        const int* __restrict__ row_start, const int* __restrict__ row_end,
        const int* __restrict__ csr_src, const uint4* __restrict__ Ah,
        const float4* __restrict__ feat4, const float* __restrict__ norm,
        const float* __restrict__ alpha, float4* __restrict__ G,
        uint4* __restrict__ A2h, int n, int h) {
    int wave = blockIdx.x * (blockDim.x >> 6) + (threadIdx.x >> 6);
    int lane = threadIdx.x & 63;
    int g  = lane >> 4;
    int eo = (lane >> 1) & 7;
    int q  = lane & 1;
    int r = wave * 4 + g;
    int s0 = 0, e1 = 0;
    if (r < n) { s0 = row_start[r]; e1 = row_end[r]; }
    float acc[8];
    #pragma unroll
    for (int i = 0; i < 8; ++i) acc[i] = 0.f;
    int j = s0 + eo;
    for (; j + 8 < e1; j += 16) {
        int sa = csr_src[j];
        int sb = csr_src[j + 8];
        uint4 va = Ah[(size_t)sa * 2 + q];
        uint4 vb = Ah[(size_t)sb * 2 + q];
        ACC_H(va);
        ACC_H(vb);
    }
    if (j < e1) {
        int sa = csr_src[j];
        uint4 va = Ah[(size_t)sa * 2 + q];
        ACC_H(va);
    }
    #pragma unroll
    for (int i = 0; i < 8; ++i) {
        acc[i] += __shfl_xor(acc[i], 2);
        acc[i] += __shfl_xor(acc[i], 4);
        acc[i] += __shfl_xor(acc[i], 8);
    }
    if (eo == 0 && r < n) {
        float nv = norm[r];
        float a0 = alpha[0], a1 = alpha[1];
        // this lane owns global features [h*16 + q*8, +8) = 2 float4s
        size_t base = (size_t)r * 8 + h * 4 + q * 2;
        float4 f0 = feat4[base], f1 = feat4[base + 1];
        float hh[8];
        #pragma unroll
        for (int i = 0; i < 8; ++i) hh[i] = acc[i] * nv;
        G[base]     = make_float4(fmaf(a1, hh[0], a0 * f0.x), fmaf(a1, hh[1], a0 * f0.y),
                                  fmaf(a1, hh[2], a0 * f0.z), fmaf(a1, hh[3], a0 * f0.w));
        G[base + 1] = make_float4(fmaf(a1, hh[4], a0 * f1.x), fmaf(a1, hh[5], a0 * f1.y),
                                  fmaf(a1, hh[6], a0 * f1.z), fmaf(a1, hh[7], a0 * f1.w));
        uint4 o;
        o.x = f2bf2(hh[0] * nv, hh[1] * nv);
        o.y = f2bf2(hh[2] * nv, hh[3] * nv);
        o.z = f2bf2(hh[4] * nv, hh[5] * nv);
        o.w = f2bf2(hh[6] * nv, hh[7] * nv);
        A2h[(size_t)r * 2 + q] = o;
    }
}

__global__ __launch_bounds__(256) void gather2_kernel(
        const int* __restrict__ row_start, const int* __restrict__ row_end,
        const int* __restrict__ csr_src, const uint4* __restrict__ Ah,
        const float* __restrict__ norm, const float* __restrict__ alpha,
        float4* __restrict__ G, int n, int h) {
    int wave = blockIdx.x * (blockDim.x >> 6) + (threadIdx.x >> 6);
    int lane = threadIdx.x & 63;
    int g  = lane >> 4;
    int eo = (lane >> 1) & 7;
    int q  = lane & 1;
    int r = wave * 4 + g;
    int s0 = 0, e1 = 0;
    if (r < n) { s0 = row_start[r]; e1 = row_end[r]; }
    float acc[8];
    #pragma unroll
    for (int i = 0; i < 8; ++i) acc[i] = 0.f;
    int j = s0 + eo;
    for (; j + 8 < e1; j += 16) {
        int sa = csr_src[j];
        int sb = csr_src[j + 8];
        uint4 va = Ah[(size_t)sa * 2 + q];
        uint4 vb = Ah[(size_t)sb * 2 + q];
        ACC_H(va);
        ACC_H(vb);
    }
    if (j < e1) {
        int sa = csr_src[j];
        uint4 va = Ah[(size_t)sa * 2 + q];
        ACC_H(va);
    }
    #pragma unroll
    for (int i = 0; i < 8; ++i) {
        acc[i] += __shfl_xor(acc[i], 2);
        acc[i] += __shfl_xor(acc[i], 4);
        acc[i] += __shfl_xor(acc[i], 8);
    }
    if (eo == 0 && r < n) {
        float nv = norm[r];
        float a2 = alpha[2];
        size_t base = (size_t)r * 8 + h * 4 + q * 2;
        float4 g0 = G[base], g1 = G[base + 1];
        G[base]     = make_float4(fmaf(a2, acc[0] * nv, g0.x), fmaf(a2, acc[1] * nv, g0.y),
                                  fmaf(a2, acc[2] * nv, g0.z), fmaf(a2, acc[3] * nv, g0.w));
        G[base + 1] = make_float4(fmaf(a2, acc[4] * nv, g1.x), fmaf(a2, acc[5] * nv, g1.y),
                                  fmaf(a2, acc[6] * nv, g1.z), fmaf(a2, acc[7] * nv, g1.w));
    }
}

// ---------------- in-place row GEMM: out = g @ W^T + 3b ----------------
__global__ void gemm_kernel(float* __restrict__ g,
                            const float* __restrict__ W,
                            const float* __restrict__ b, int n) {
    __shared__ float Wl[D][D + 1];
    __shared__ float gl[8][D];
    int tid = threadIdx.x;
    for (int k = tid; k < D * D; k += 256) Wl[k >> 5][k & 31] = W[k];
    int v0 = blockIdx.x * 8;
    int lr = tid >> 5;
    int o  = tid & 31;
    int v = v0 + lr;
    if (v < n) gl[lr][o] = g[(size_t)v * D + o];
    __syncthreads();
    if (v < n) {
        float acc = 3.0f * b[o];
        #pragma unroll
        for (int k = 0; k < D; ++k) acc = fmaf(gl[lr][k], Wl[o][k], acc);
        g[(size_t)v * D + o] = acc;
    }
}

extern "C" void kernel_launch(void* const* d_in, const int* in_sizes, int n_in,
                              void* d_out, int out_size, void* d_ws, size_t ws_size,
                              hipStream_t stream) {
    const float* feat  = (const float*)d_in[0];
    const int*   src   = (const int*)  d_in[1];
    const int*   dst   = (const int*)  d_in[2];
    const float* W     = (const float*)d_in[3];
    const float* b     = (const float*)d_in[4];
    const float* alpha = (const float*)d_in[5];

    const int N  = in_sizes[0] / D;
    const int E  = in_sizes[1];
    const int BT = 256;
    const int NB = (N + BWID - 1) >> BSH;
    const int GB = (E + CHUNK - 1) / CHUNK;
    const int gblocks = (N + 15) / 16;    // 4 waves/block x 4 rows/wave
    const int gemm_blocks = (N + 7) / 8;
    float4* G = (float4*)d_out;

    // ws (u32 units): A1h0[8N] A1h1[8N] A2h0[8N] A2h1[8N] cnt[GB*NB] off[GB*NB]
    //                 btot[NB] bbase[NB+1] ebuf[E] csr[E] rs[N] re[N] norm[N]
    size_t needA = ((size_t)32 * N + 2 * (size_t)GB * NB + 2 * NB + 1
                    + 2 * (size_t)E + 3 * (size_t)N) * 4;

    if (ws_size >= needA && NB <= 256 && GB <= 512 && N < (1 << 23)) {
        unsigned* A1h0      = (unsigned*)d_ws;
        unsigned* A1h1      = A1h0 + (size_t)8 * N;
        unsigned* A2h0      = A1h1 + (size_t)8 * N;
        unsigned* A2h1      = A2h0 + (size_t)8 * N;
        int*      cnt       = (int*)(A2h1 + (size_t)8 * N);
        int*      off       = cnt + (size_t)GB * NB;
        int*      btot      = off + (size_t)GB * NB;
        int*      bbase     = btot + NB;
        unsigned* ebuf      = (unsigned*)(bbase + NB + 1);
        int*      csr_src   = (int*)(ebuf + E);
        int*      row_start = csr_src + E;
        int*      row_end   = row_start + N;
        float*    norm      = (float*)(row_end + N);

        p1_count_kernel<<<GB, BT, 0, stream>>>(dst, cnt, E, NB);
        red_kernel<<<NB, BT, 0, stream>>>(cnt, btot, GB, NB);
        scanb_kernel<<<1, BT, 0, stream>>>(btot, bbase, NB);
        off_kernel<<<NB, BT, 0, stream>>>(cnt, bbase, off, GB, NB);
        p3_scatter_kernel<<<GB, BT, 0, stream>>>(src, dst, off, ebuf, E, NB);
        p4_kernel<<<NB, BT, 0, stream>>>(ebuf, bbase, row_start, row_end, norm, csr_src,
                                         feat, A1h0, A1h1, N);

        gather1_kernel<<<gblocks, BT, 0, stream>>>(row_start, row_end, csr_src,
                                                   (const uint4*)A1h0, (const float4*)feat,
                                                   norm, alpha, G, (uint4*)A2h0, N, 0);
        gather1_kernel<<<gblocks, BT, 0, stream>>>(row_start, row_end, csr_src,
                                                   (const uint4*)A1h1, (const float4*)feat,
                                                   norm, alpha, G, (uint4*)A2h1, N, 1);
        gather2_kernel<<<gblocks, BT, 0, stream>>>(row_start, row_end, csr_src,
                                                   (const uint4*)A2h0, norm, alpha, G, N, 0);
        gather2_kernel<<<gblocks, BT, 0, stream>>>(row_start, row_end, csr_src,
                                                   (const uint4*)A2h1, norm, alpha, G, N, 1);
        gemm_kernel<<<gemm_blocks, BT, 0, stream>>>((float*)G, W, b, N);
    } else {
        const int nb = (N + SCAN_CHUNK - 1) / SCAN_CHUNK;
        const int e4blocks = ((E + 3) / 4 + BT - 1) / BT;
        unsigned* A1h0      = (unsigned*)d_ws;
        unsigned* A1h1      = A1h0 + (size_t)8 * N;
        unsigned* A2h0      = A1h1 + (size_t)8 * N;
        unsigned* A2h1      = A2h0 + (size_t)8 * N;
        int*      deg       = (int*)(A2h1 + (size_t)8 * N);
        int*      pos       = deg + N;
        int*      partial   = pos + E;
        int*      row_start = partial + 256;
        int*      row_end   = row_start + N;
        int*      csr_src   = row_end + N;
        float*    norm      = (float*)(csr_src + E);

        hipMemsetAsync(deg, 0, (size_t)N * sizeof(int), stream);
        degpos_kernel<<<e4blocks, BT, 0, stream>>>(dst, deg, pos, E);
        scan1_kernel<<<nb, SCAN_T, 0, stream>>>(deg, partial, N);
        scan2_kernel<<<1, 256, 0, stream>>>(partial, nb);
        scan3_kernel<<<nb, SCAN_T, 0, stream>>>(deg, partial, row_start, row_end, norm, N);
        fillA_kernel<<<e4blocks, BT, 0, stream>>>(src, dst, pos, row_start, csr_src, E);
        prep_kernel<<<(16 * N + BT - 1) / BT, BT, 0, stream>>>(feat, norm, A1h0, A1h1, 16 * N);

        gather1_kernel<<<gblocks, BT, 0, stream>>>(row_start, row_end, csr_src,
                                                   (const uint4*)A1h0, (const float4*)feat,
                                                   norm, alpha, G, (uint4*)A2h0, N, 0);
        gather1_kernel<<<gblocks, BT, 0, stream>>>(row_start, row_end, csr_src,
                                                   (const uint4*)A1h1, (const float4*)feat,
                                                   norm, alpha, G, (uint4*)A2h1, N, 1);
        gather2_kernel<<<gblocks, BT, 0, stream>>>(row_start, row_end, csr_src,
                                                   (const uint4*)A2h0, norm, alpha, G, N, 0);
        gather2_kernel<<<gblocks, BT, 0, stream>>>(row_start, row_end, csr_src,
                                                   (const uint4*)A2h1, norm, alpha, G, N, 1);
        gemm_kernel<<<gemm_blocks, BT, 0, stream>>>((float*)G, W, b, N);
    }
}

// Round 11
// 106.624 us; speedup vs baseline: 1.4134x; 1.4134x over previous
//
#include <hip/hip_runtime.h>

#define D 32
#define CHUNK 8192        // edges per build block
#define BWID 256          // nodes per bucket
#define BSH 8             // log2(BWID)
#define NBCAP 512         // max buckets (LDS arrays in p1/p3)
#define EBCAP 6144        // max staged edges per bucket in p4 (24KB)
#define SCAN_T 256
#define SCAN_V 4
#define SCAN_CHUNK 1024

// ---------------- bf16 helpers ----------------
__device__ __forceinline__ unsigned f2bf2(float lo, float hi) {
    union { float f; unsigned u; } a, b;
    a.f = lo; b.f = hi;
    unsigned ra = a.u + 0x7FFFu + ((a.u >> 16) & 1u);   // RNE
    unsigned rb = b.u + 0x7FFFu + ((b.u >> 16) & 1u);
    return (ra >> 16) | (rb & 0xFFFF0000u);
}
__device__ __forceinline__ void bf2_unpack(unsigned u, float& lo, float& hi) {
    union { unsigned u; float f; } a, b;
    a.u = u << 16; b.u = u & 0xFFFF0000u;
    lo = a.f; hi = b.f;
}

// ================= bucketed CSR build (no global atomics) =================

__global__ void p1_count_kernel(const int* __restrict__ dst, int* __restrict__ cnt,
                                int E, int NB) {
    __shared__ int h[NBCAP];
    int blk = blockIdx.x, t = threadIdx.x;
    for (int i = t; i < NB; i += 256) h[i] = 0;
    __syncthreads();
    int base = blk * CHUNK;
    int end = min(base + CHUNK, E);
    for (int a = base + t * 4; a < end; a += 1024) {
        if (a + 3 < end) {
            int4 d = *(const int4*)(dst + a);
            atomicAdd(&h[d.x >> BSH], 1);
            atomicAdd(&h[d.y >> BSH], 1);
            atomicAdd(&h[d.z >> BSH], 1);
            atomicAdd(&h[d.w >> BSH], 1);
        } else {
            for (int e = a; e < end && e < a + 4; ++e) atomicAdd(&h[dst[e] >> BSH], 1);
        }
    }
    __syncthreads();
    for (int i = t; i < NB; i += 256) cnt[(size_t)blk * NB + i] = h[i];
}

__global__ void red_kernel(const int* __restrict__ cnt, int* __restrict__ btot,
                           int GB, int NB) {
    __shared__ int s[256];
    int b = blockIdx.x, t = threadIdx.x;
    int acc = 0;
    for (int g = t; g < GB; g += 256) acc += cnt[(size_t)g * NB + b];
    s[t] = acc;
    __syncthreads();
    for (int off = 128; off > 0; off >>= 1) {
        if (t < off) s[t] += s[t + off];
        __syncthreads();
    }
    if (t == 0) btot[b] = s[0];
}

// chunked exclusive scan over NB bucket totals (NB may exceed 256)
__global__ void scanb_kernel(const int* __restrict__ btot, int* __restrict__ bbase, int NB) {
    __shared__ int s[256];
    __shared__ int carry;
    int t = threadIdx.x;
    if (t == 0) carry = 0;
    __syncthreads();
    for (int base = 0; base < NB; base += 256) {
        int v = (base + t < NB) ? btot[base + t] : 0;
        s[t] = v;
        __syncthreads();
        for (int off = 1; off < 256; off <<= 1) {
            int x = (t >= off) ? s[t - off] : 0;
            __syncthreads();
            s[t] += x;
            __syncthreads();
        }
        if (base + t < NB) bbase[base + t] = carry + s[t] - v;
        __syncthreads();
        if (t == 255) carry += s[255];
        __syncthreads();
    }
    if (t == 0) bbase[NB] = carry;
}

__global__ void off_kernel(const int* __restrict__ cnt, const int* __restrict__ bbase,
                           int* __restrict__ off, int GB, int NB) {
    __shared__ int st[256];
    int b = blockIdx.x, t = threadIdx.x;
    int g0 = 2 * t, g1 = 2 * t + 1;
    int c0 = (g0 < GB) ? cnt[(size_t)g0 * NB + b] : 0;
    int c1 = (g1 < GB) ? cnt[(size_t)g1 * NB + b] : 0;
    int pair = c0 + c1;
    st[t] = pair;
    __syncthreads();
    for (int o = 1; o < 256; o <<= 1) {
        int x = (t >= o) ? st[t - o] : 0;
        __syncthreads();
        st[t] += x;
        __syncthreads();
    }
    int ex = bbase[b] + st[t] - pair;
    if (g0 < GB) off[(size_t)g0 * NB + b] = ex;
    if (g1 < GB) off[(size_t)g1 * NB + b] = ex + c0;
}

__global__ void p3_scatter_kernel(const int* __restrict__ src, const int* __restrict__ dst,
                                  const int* __restrict__ off, unsigned* __restrict__ ebuf,
                                  int E, int NB) {
    __shared__ int cur[NBCAP];
    int blk = blockIdx.x, t = threadIdx.x;
    for (int i = t; i < NB; i += 256) cur[i] = off[(size_t)blk * NB + i];
    __syncthreads();
    int base = blk * CHUNK;
    int end = min(base + CHUNK, E);
    for (int a = base + t * 4; a < end; a += 1024) {
        if (a + 3 < end) {
            int4 d = *(const int4*)(dst + a);
            int4 s = *(const int4*)(src + a);
            int p0 = atomicAdd(&cur[d.x >> BSH], 1);
            int p1 = atomicAdd(&cur[d.y >> BSH], 1);
            int p2 = atomicAdd(&cur[d.z >> BSH], 1);
            int p3 = atomicAdd(&cur[d.w >> BSH], 1);
            ebuf[p0] = ((unsigned)(d.x & (BWID - 1)) << 23) | (unsigned)s.x;
            ebuf[p1] = ((unsigned)(d.y & (BWID - 1)) << 23) | (unsigned)s.y;
            ebuf[p2] = ((unsigned)(d.z & (BWID - 1)) << 23) | (unsigned)s.z;
            ebuf[p3] = ((unsigned)(d.w & (BWID - 1)) << 23) | (unsigned)s.w;
        } else {
            for (int e = a; e < end && e < a + 4; ++e) {
                int dv = dst[e];
                int p = atomicAdd(&cur[dv >> BSH], 1);
                ebuf[p] = ((unsigned)(dv & (BWID - 1)) << 23) | (unsigned)src[e];
            }
        }
    }
}

// ---- P4: per-bucket finalize (LDS-staged edges) -> rows/norm/csr + uint4 bf16 prep ----
__global__ void p4_kernel(const unsigned* __restrict__ ebuf, const int* __restrict__ bbase,
                          int* __restrict__ row_start, int* __restrict__ row_end,
                          float* __restrict__ norm, int* __restrict__ csr_src,
                          const float4* __restrict__ feat4, uint4* __restrict__ A1q, int N) {
    __shared__ unsigned eb[EBCAP];
    __shared__ int deg2[BWID];
    __shared__ int rs[BWID];
    __shared__ int st[256];
    int b = blockIdx.x, t = threadIdx.x;
    int node0 = b << BSH;
    int nn = min(BWID, N - node0);
    int e0 = bbase[b], e1 = bbase[b + 1];
    int ne = e1 - e0;
    bool staged = (ne <= EBCAP);

    if (t < BWID) deg2[t] = 0;
    __syncthreads();
    if (staged) {
        for (int j = t; j < ne; j += 256) {
            unsigned v = ebuf[e0 + j];
            eb[j] = v;
            atomicAdd(&deg2[v >> 23], 1);
        }
    } else {
        for (int j = t; j < ne; j += 256)
            atomicAdd(&deg2[ebuf[e0 + j] >> 23], 1);
    }
    __syncthreads();
    // exclusive scan over 256 degrees (1/thread)
    int dg = deg2[t];
    st[t] = dg;
    __syncthreads();
    for (int off = 1; off < 256; off <<= 1) {
        int v = (t >= off) ? st[t - off] : 0;
        __syncthreads();
        st[t] += v;
        __syncthreads();
    }
    int ex = st[t] - dg;
    rs[t] = ex;
    if (t < nn) {
        row_start[node0 + t] = e0 + ex;
        row_end[node0 + t]   = e0 + ex + dg;
        norm[node0 + t] = rsqrtf(fmaxf((float)dg, 1.0f));
    }
    __syncthreads();
    // scatter csr within the bucket window
    if (staged) {
        for (int j = t; j < ne; j += 256) {
            unsigned v = eb[j];
            int p = atomicAdd(&rs[v >> 23], 1);
            csr_src[e0 + p] = (int)(v & 0x7FFFFF);
        }
    } else {
        for (int j = t; j < ne; j += 256) {
            unsigned v = ebuf[e0 + j];
            int p = atomicAdd(&rs[v >> 23], 1);
            csr_src[e0 + p] = (int)(v & 0x7FFFFF);
        }
    }
    // fused prep: A1q = bf16(feat * norm), coalesced uint4 writes
    for (int c = t; c < nn * 4; c += 256) {
        int nl = c >> 2, q = c & 3;
        float nv = rsqrtf(fmaxf((float)deg2[nl], 1.0f));
        size_t rf = (size_t)(node0 + nl) * 8 + q * 2;
        float4 f0 = feat4[rf], f1 = feat4[rf + 1];
        uint4 o;
        o.x = f2bf2(f0.x * nv, f0.y * nv);
        o.y = f2bf2(f0.z * nv, f0.w * nv);
        o.z = f2bf2(f1.x * nv, f1.y * nv);
        o.w = f2bf2(f1.z * nv, f1.w * nv);
        A1q[(size_t)(node0 + nl) * 4 + q] = o;
    }
}

// ================= fallback build (global atomics) =================
__global__ void degpos_kernel(const int* __restrict__ dst, int* __restrict__ deg,
                              int* __restrict__ pos, int E) {
    int t = blockIdx.x * blockDim.x + threadIdx.x;
    int base = t * 4;
    if (base + 3 < E) {
        int4 d = *(const int4*)(dst + base);
        int4 p;
        p.x = atomicAdd(&deg[d.x], 1);
        p.y = atomicAdd(&deg[d.y], 1);
        p.z = atomicAdd(&deg[d.z], 1);
        p.w = atomicAdd(&deg[d.w], 1);
        *(int4*)(pos + base) = p;
    } else if (base < E) {
        for (int e = base; e < E; ++e) pos[e] = atomicAdd(&deg[dst[e]], 1);
    }
}

__global__ void scan1_kernel(const int* __restrict__ deg, int* __restrict__ partial, int n) {
    __shared__ int sdata[SCAN_T];
    int base = blockIdx.x * SCAN_CHUNK + threadIdx.x * SCAN_V;
    int s = 0;
    #pragma unroll
    for (int k = 0; k < SCAN_V; ++k) { int i = base + k; if (i < n) s += deg[i]; }
    sdata[threadIdx.x] = s;
    __syncthreads();
    for (int off = SCAN_T / 2; off > 0; off >>= 1) {
        if (threadIdx.x < off) sdata[threadIdx.x] += sdata[threadIdx.x + off];
        __syncthreads();
    }
    if (threadIdx.x == 0) partial[blockIdx.x] = sdata[0];
}

__global__ void scan2_kernel(int* __restrict__ partial, int nb) {
    __shared__ int sdata[256];
    int v = (threadIdx.x < nb) ? partial[threadIdx.x] : 0;
    sdata[threadIdx.x] = v;
    __syncthreads();
    for (int off = 1; off < 256; off <<= 1) {
        int t = (threadIdx.x >= off) ? sdata[threadIdx.x - off] : 0;
        __syncthreads();
        sdata[threadIdx.x] += t;
        __syncthreads();
    }
    if (threadIdx.x < nb) partial[threadIdx.x] = sdata[threadIdx.x] - v;
}

__global__ void scan3_kernel(const int* __restrict__ deg, const int* __restrict__ partial,
                             int* __restrict__ row_start, int* __restrict__ row_end,
                             float* __restrict__ norm, int n) {
    __shared__ int sdata[SCAN_T];
    int base = blockIdx.x * SCAN_CHUNK + threadIdx.x * SCAN_V;
    int v[SCAN_V];
    int s = 0;
    #pragma unroll
    for (int k = 0; k < SCAN_V; ++k) { int i = base + k; v[k] = (i < n) ? deg[i] : 0; s += v[k]; }
    int self = s;
    sdata[threadIdx.x] = s;
    __syncthreads();
    for (int off = 1; off < SCAN_T; off <<= 1) {
        int t = (threadIdx.x >= off) ? sdata[threadIdx.x - off] : 0;
        __syncthreads();
        sdata[threadIdx.x] += t;
        __syncthreads();
    }
    int run = partial[blockIdx.x] + sdata[threadIdx.x] - self;
    #pragma unroll
    for (int k = 0; k < SCAN_V; ++k) {
        int i = base + k;
        if (i < n) {
            row_start[i] = run;
            row_end[i]   = run + v[k];
            norm[i] = rsqrtf(fmaxf((float)v[k], 1.0f));
            run += v[k];
        }
    }
}

__global__ void fillA_kernel(const int* __restrict__ src, const int* __restrict__ dst,
                             const int* __restrict__ pos, const int* __restrict__ row_start,
                             int* __restrict__ csr_src, int E) {
    int t = blockIdx.x * blockDim.x + threadIdx.x;
    int base = t * 4;
    if (base + 3 < E) {
        int4 d = *(const int4*)(dst + base);
        int4 p = *(const int4*)(pos + base);
        int4 s = *(const int4*)(src + base);
        csr_src[row_start[d.x] + p.x] = s.x;
        csr_src[row_start[d.y] + p.y] = s.y;
        csr_src[row_start[d.z] + p.z] = s.z;
        csr_src[row_start[d.w] + p.w] = s.w;
    } else if (base < E) {
        for (int e = base; e < E; ++e)
            csr_src[row_start[dst[e]] + pos[e]] = src[e];
    }
}

__global__ void prep_kernel(const float4* __restrict__ feat4, const float* __restrict__ norm,
                            uint4* __restrict__ A1q, int nchunk) {
    int i = blockIdx.x * blockDim.x + threadIdx.x;
    if (i >= nchunk) return;
    int v = i >> 2;
    float nv = norm[v];
    float4 f0 = feat4[(size_t)i * 2], f1 = feat4[(size_t)i * 2 + 1];
    uint4 o;
    o.x = f2bf2(f0.x * nv, f0.y * nv);
    o.y = f2bf2(f0.z * nv, f0.w * nv);
    o.z = f2bf2(f1.x * nv, f1.y * nv);
    o.w = f2bf2(f1.z * nv, f1.w * nv);
    A1q[i] = o;
}

// ================= 4-rows-per-wave bf16 gathers (R8, proven) =================
#define ACC_EDGE(V)                                              \
    { float lo_, hi_;                                            \
      bf2_unpack((V).x, lo_, hi_); acc[0] += lo_; acc[1] += hi_; \
      bf2_unpack((V).y, lo_, hi_); acc[2] += lo_; acc[3] += hi_; \
      bf2_unpack((V).z, lo_, hi_); acc[4] += lo_; acc[5] += hi_; \
      bf2_unpack((V).w, lo_, hi_); acc[6] += lo_; acc[7] += hi_; }

__global__ __launch_bounds__(256) void gather1_kernel(
        const int* __restrict__ row_start, const int* __restrict__ row_end,
        const int* __restrict__ csr_src, const uint4* __restrict__ A1q,
        const float4* __restrict__ feat4, const float* __restrict__ norm,
        const float* __restrict__ alpha, float4* __restrict__ G,
        uint4* __restrict__ A2q, int n) {
    int wave = blockIdx.x * (blockDim.x >> 6) + (threadIdx.x >> 6);
    int lane = threadIdx.x & 63;
    int g  = lane >> 4;
    int eo = (lane >> 2) & 3;
    int q  = lane & 3;
    int r = wave * 4 + g;
    int s0 = 0, e1 = 0;
    if (r < n) { s0 = row_start[r]; e1 = row_end[r]; }
    float acc[8];
    #pragma unroll
    for (int i = 0; i < 8; ++i) acc[i] = 0.f;
    int j = s0 + eo;
    for (; j + 4 < e1; j += 8) {
        int sa = csr_src[j];
        int sb = csr_src[j + 4];
        uint4 va = A1q[(size_t)sa * 4 + q];
        uint4 vb = A1q[(size_t)sb * 4 + q];
        ACC_EDGE(va);
        ACC_EDGE(vb);
    }
    if (j < e1) {
        int sa = csr_src[j];
        uint4 va = A1q[(size_t)sa * 4 + q];
        ACC_EDGE(va);
    }
    #pragma unroll
    for (int i = 0; i < 8; ++i) {
        acc[i] += __shfl_xor(acc[i], 4);
        acc[i] += __shfl_xor(acc[i], 8);
    }
    if (eo == 0 && r < n) {
        float nv = norm[r];
        float a0 = alpha[0], a1 = alpha[1];
        size_t rf = (size_t)r * 8 + q * 2;
        float4 f0 = feat4[rf], f1 = feat4[rf + 1];
        float h[8];
        #pragma unroll
        for (int i = 0; i < 8; ++i) h[i] = acc[i] * nv;
        G[rf]     = make_float4(fmaf(a1, h[0], a0 * f0.x), fmaf(a1, h[1], a0 * f0.y),
                                fmaf(a1, h[2], a0 * f0.z), fmaf(a1, h[3], a0 * f0.w));
        G[rf + 1] = make_float4(fmaf(a1, h[4], a0 * f1.x), fmaf(a1, h[5], a0 * f1.y),
                                fmaf(a1, h[6], a0 * f1.z), fmaf(a1, h[7], a0 * f1.w));
        uint4 o;
        o.x = f2bf2(h[0] * nv, h[1] * nv);
        o.y = f2bf2(h[2] * nv, h[3] * nv);
        o.z = f2bf2(h[4] * nv, h[5] * nv);
        o.w = f2bf2(h[6] * nv, h[7] * nv);
        A2q[(size_t)r * 4 + q] = o;
    }
}

__global__ __launch_bounds__(256) void gather2_kernel(
        const int* __restrict__ row_start, const int* __restrict__ row_end,
        const int* __restrict__ csr_src, const uint4* __restrict__ A2q,
        const float* __restrict__ norm, const float* __restrict__ alpha,
        const float* __restrict__ W, const float* __restrict__ b,
        float4* __restrict__ G, int n) {
    __shared__ float Wl[D][D + 1];
    __shared__ float pbuf[4][4][D];     // [wave][row group][feat]
    int tid = threadIdx.x;
    for (int k = tid; k < D * D; k += 256) Wl[k >> 5][k & 31] = W[k];
    __syncthreads();

    int wv = tid >> 6;
    int wave = blockIdx.x * 4 + wv;
    int lane = tid & 63;
    int g  = lane >> 4;
    int eo = (lane >> 2) & 3;
    int q  = lane & 3;
    int r = wave * 4 + g;
    int s0 = 0, e1 = 0;
    if (r < n) { s0 = row_start[r]; e1 = row_end[r]; }
    float acc[8];
    #pragma unroll
    for (int i = 0; i < 8; ++i) acc[i] = 0.f;
    int j = s0 + eo;
    for (; j + 4 < e1; j += 8) {
        int sa = csr_src[j];
        int sb = csr_src[j + 4];
        uint4 va = A2q[(size_t)sa * 4 + q];
        uint4 vb = A2q[(size_t)sb * 4 + q];
        ACC_EDGE(va);
        ACC_EDGE(vb);
    }
    if (j < e1) {
        int sa = csr_src[j];
        uint4 va = A2q[(size_t)sa * 4 + q];
        ACC_EDGE(va);
    }
    #pragma unroll
    for (int i = 0; i < 8; ++i) {
        acc[i] += __shfl_xor(acc[i], 4);
        acc[i] += __shfl_xor(acc[i], 8);
    }
    if (eo == 0 && r < n) {
        float nv = norm[r];
        float a2 = alpha[2];
        size_t rf = (size_t)r * 8 + q * 2;
        float4 g0 = G[rf], g1 = G[rf + 1];
        float4 p0 = make_float4(fmaf(a2, acc[0] * nv, g0.x), fmaf(a2, acc[1] * nv, g0.y),
                                fmaf(a2, acc[2] * nv, g0.z), fmaf(a2, acc[3] * nv, g0.w));
        float4 p1 = make_float4(fmaf(a2, acc[4] * nv, g1.x), fmaf(a2, acc[5] * nv, g1.y),
                                fmaf(a2, acc[6] * nv, g1.z), fmaf(a2, acc[7] * nv, g1.w));
        *(float4*)&pbuf[wv][g][q * 8]     = p0;
        *(float4*)&pbuf[wv][g][q * 8 + 4] = p1;
    }
    asm volatile("s_waitcnt lgkmcnt(0)" ::: "memory");

    int o  = lane & 31;
    int rr = lane >> 5;
    #pragma unroll
    for (int rp = 0; rp < 2; ++rp) {
        int gg = rp * 2 + rr;
        int row = wave * 4 + gg;
        if (row < n) {
            float acco = 0.f;
            #pragma unroll
            for (int k = 0; k < D; ++k)
                acco = fmaf(pbuf[wv][gg][k], Wl[o][k], acco);
            ((float*)G)[(size_t)row * D + o] = acco + 3.0f * b[o];
        }
    }
}

extern "C" void kernel_launch(void* const* d_in, const int* in_sizes, int n_in,
                              void* d_out, int out_size, void* d_ws, size_t ws_size,
                              hipStream_t stream) {
    const float* feat  = (const float*)d_in[0];
    const int*   src   = (const int*)  d_in[1];
    const int*   dst   = (const int*)  d_in[2];
    const float* W     = (const float*)d_in[3];
    const float* b     = (const float*)d_in[4];
    const float* alpha = (const float*)d_in[5];

    const int N  = in_sizes[0] / D;
    const int E  = in_sizes[1];
    const int BT = 256;
    const int NB = (N + BWID - 1) >> BSH;
    const int GB = (E + CHUNK - 1) / CHUNK;
    const int gblocks = (N + 15) / 16;    // 4 waves/block x 4 rows/wave
    float4* G = (float4*)d_out;

    // ws (u32 units): A1q[16N] A2q[16N] cnt[GB*NB] off[GB*NB] btot[NB]
    //                 bbase[NB+1] ebuf[E] csr[E] rs[N] re[N] norm[N]
    size_t needA = ((size_t)32 * N + 2 * (size_t)GB * NB + 2 * NB + 1
                    + 2 * (size_t)E + 3 * (size_t)N) * 4;

    if (ws_size >= needA && NB <= NBCAP && GB <= 512 && N < (1 << 23)) {
        unsigned* A1q       = (unsigned*)d_ws;
        unsigned* A2q       = A1q + (size_t)16 * N;
        int*      cnt       = (int*)(A2q + (size_t)16 * N);
        int*      off       = cnt + (size_t)GB * NB;
        int*      btot      = off + (size_t)GB * NB;
        int*      bbase     = btot + NB;
        unsigned* ebuf      = (unsigned*)(bbase + NB + 1);
        int*      csr_src   = (int*)(ebuf + E);
        int*      row_start = csr_src + E;
        int*      row_end   = row_start + N;
        float*    norm      = (float*)(row_end + N);

        p1_count_kernel<<<GB, BT, 0, stream>>>(dst, cnt, E, NB);
        red_kernel<<<NB, BT, 0, stream>>>(cnt, btot, GB, NB);
        scanb_kernel<<<1, BT, 0, stream>>>(btot, bbase, NB);
        off_kernel<<<NB, BT, 0, stream>>>(cnt, bbase, off, GB, NB);
        p3_scatter_kernel<<<GB, BT, 0, stream>>>(src, dst, off, ebuf, E, NB);
        p4_kernel<<<NB, BT, 0, stream>>>(ebuf, bbase, row_start, row_end, norm, csr_src,
                                         (const float4*)feat, (uint4*)A1q, N);
        gather1_kernel<<<gblocks, BT, 0, stream>>>(row_start, row_end, csr_src,
                                                   (const uint4*)A1q, (const float4*)feat,
                                                   norm, alpha, G, (uint4*)A2q, N);
        gather2_kernel<<<gblocks, BT, 0, stream>>>(row_start, row_end, csr_src,
                                                   (const uint4*)A2q, norm, alpha,
                                                   W, b, G, N);
    } else {
        const int nb = (N + SCAN_CHUNK - 1) / SCAN_CHUNK;
        const int e4blocks = ((E + 3) / 4 + BT - 1) / BT;
        unsigned* A1q       = (unsigned*)d_ws;
        unsigned* A2q       = A1q + (size_t)16 * N;
        int*      deg       = (int*)(A2q + (size_t)16 * N);
        int*      pos       = deg + N;
        int*      partial   = pos + E;
        int*      row_start = partial + 256;
        int*      row_end   = row_start + N;
        int*      csr_src   = row_end + N;
        float*    norm      = (float*)(csr_src + E);

        hipMemsetAsync(deg, 0, (size_t)N * sizeof(int), stream);
        degpos_kernel<<<e4blocks, BT, 0, stream>>>(dst, deg, pos, E);
        scan1_kernel<<<nb, SCAN_T, 0, stream>>>(deg, partial, N);
        scan2_kernel<<<1, 256, 0, stream>>>(partial, nb);
        scan3_kernel<<<nb, SCAN_T, 0, stream>>>(deg, partial, row_start, row_end, norm, N);
        fillA_kernel<<<e4blocks, BT, 0, stream>>>(src, dst, pos, row_start, csr_src, E);
        prep_kernel<<<(4 * N + BT - 1) / BT, BT, 0, stream>>>(
            (const float4*)feat, norm, (uint4*)A1q, 4 * N);
        gather1_kernel<<<gblocks, BT, 0, stream>>>(row_start, row_end, csr_src,
                                                   (const uint4*)A1q, (const float4*)feat,
                                                   norm, alpha, G, (uint4*)A2q, N);
        gather2_kernel<<<gblocks, BT, 0, stream>>>(row_start, row_end, csr_src,
                                                   (const uint4*)A2q, norm, alpha,
                                                   W, b, G, N);
    }
}